// Round 7
// baseline (340.480 us; speedup 1.0000x reference)
//
#include <hip/hip_runtime.h>
#include <cstdint>
#include <cstddef>

// Problem constants
#define BB 4
#define TT 2048
#define DD 1024
#define HH 8
#define DH 64
#define EE 5
#define MM (BB*TT)          // 8192 rows
#define PLD 1344            // proj leading dim (q 512 | k 512 | xv 320)
#define NWT 1408            // padded N for MFMA proj (11 * 128)

typedef short short8 __attribute__((ext_vector_type(8)));
typedef float f32x4  __attribute__((ext_vector_type(4)));
typedef float f32x16 __attribute__((ext_vector_type(16)));
typedef unsigned int u32x2 __attribute__((ext_vector_type(2)));

// ---------- bf16 helpers ----------
__device__ __forceinline__ float bflo(uint32_t u) { union { uint32_t i; float f; } v; v.i = u << 16; return v.f; }
__device__ __forceinline__ float bfhi(uint32_t u) { union { uint32_t i; float f; } v; v.i = u & 0xFFFF0000u; return v.f; }
__device__ __forceinline__ float bf2f(uint16_t u) { union { uint32_t i; float f; } v; v.i = ((uint32_t)u) << 16; return v.f; }
// cheap bf16 pack: round-half-up (+0x8000) then v_perm_b32 pair-pack (1 op).
__device__ __forceinline__ uint32_t pkbf(float a, float b) {
  uint32_t ua = __float_as_uint(a) + 0x8000u;
  uint32_t ub = __float_as_uint(b) + 0x8000u;
  return __builtin_amdgcn_perm(ub, ua, 0x07060302u);  // [ua.b2,ua.b3,ub.b2,ub.b3]
}
__device__ __forceinline__ uint16_t bfr1(float f) {
  return (uint16_t)((__float_as_uint(f) + 0x8000u) >> 16);
}
// RNE pair-pack via hardware cvt (1 op); lo = a, hi = b
__device__ __forceinline__ uint32_t cvtpk(float a, float b) {
  uint32_t r;
  asm("v_cvt_pk_bf16_f32 %0, %1, %2" : "=v"(r) : "v"(a), "v"(b));
  return r;
}

// ---------- async global->LDS, 16B per lane (dest = wave base + lane*16) ----------
__device__ __forceinline__ void gload16(const void* g, void* l) {
  __builtin_amdgcn_global_load_lds(
      (const __attribute__((address_space(1))) uint32_t*)g,
      (__attribute__((address_space(3))) uint32_t*)l, 16, 0, 0);
}

// ---------- pack W^T bf16 [NWT][1024] for MFMA proj (LDS tile transpose) ----------
__global__ __launch_bounds__(256) void pack_wt_kernel(
    const float* __restrict__ Wq, const float* __restrict__ Wk,
    const float* __restrict__ Wv, uint16_t* __restrict__ Wt)
{
  __shared__ __align__(16) uint16_t Ts[64 * 68];
  int k0 = blockIdx.x * 64, n0 = blockIdx.y * 64;
  int t = threadIdx.x;
#pragma unroll
  for (int rep = 0; rep < 16; ++rep) {
    int li = rep * 256 + t;
    int kl = li >> 6, nl = li & 63;
    int k = k0 + kl, n = n0 + nl;
    float v = 0.f;
    if (n < 512)       v = Wq[k * 512 + n];
    else if (n < 1024) v = Wk[k * 512 + (n - 512)];
    else if (n < 1344) { int nn = n - 1024; v = Wv[((size_t)(nn >> 6) * 1024 + k) * 64 + (nn & 63)]; }
    Ts[kl * 68 + nl] = bfr1(v);
  }
  __syncthreads();
#pragma unroll
  for (int rep = 0; rep < 16; ++rep) {
    int li = rep * 256 + t;
    int nl = li >> 6, kl = li & 63;
    Wt[(size_t)(n0 + nl) * 1024 + k0 + kl] = Ts[kl * 68 + nl];
  }
}

// ---------- pack Wo[320][1024] fp32 -> WoT bf16 [1024][320] ----------
__global__ __launch_bounds__(256) void pack_wot_kernel(
    const float* __restrict__ Wo, uint16_t* __restrict__ WoT)
{
  __shared__ __align__(16) uint16_t Ts[64 * 68];
  int k0 = blockIdx.x * 64, n0 = blockIdx.y * 64;
  int t = threadIdx.x;
#pragma unroll
  for (int rep = 0; rep < 16; ++rep) {
    int li = rep * 256 + t;
    int kl = li >> 6, nl = li & 63;
    Ts[kl * 68 + nl] = bfr1(Wo[(size_t)(k0 + kl) * 1024 + n0 + nl]);
  }
  __syncthreads();
#pragma unroll
  for (int rep = 0; rep < 16; ++rep) {
    int li = rep * 256 + t;
    int nl = li >> 6, kl = li & 63;
    WoT[(size_t)(n0 + nl) * 320 + k0 + kl] = Ts[kl * 68 + nl];
  }
}

// ---------- x -> bf16 ----------
__global__ __launch_bounds__(256) void xbf_kernel(const float* __restrict__ x, uint16_t* __restrict__ xb)
{
  int i = (blockIdx.x * 256 + threadIdx.x) * 4;
  float4 v = *(const float4*)(x + i);
  uint2 o;
  o.x = pkbf(v.x, v.y);
  o.y = pkbf(v.z, v.w);
  *(uint2*)(xb + i) = o;
}

// ---------- top-2 of 5 (lax.top_k tie rule: lower index wins) ----------
__device__ __forceinline__ void top2_5(float g0, float g1, float g2, float g3, float g4,
                                       int& i1, float& b1, int& i2, float& b2) {
  i1 = 0; b1 = g0;
  if (g1 > b1) { b1 = g1; i1 = 1; }
  if (g2 > b1) { b1 = g2; i1 = 2; }
  if (g3 > b1) { b1 = g3; i1 = 3; }
  if (g4 > b1) { b1 = g4; i1 = 4; }
  i2 = -1; b2 = -__builtin_inff();
  if (i1 != 0 && g0 > b2) { b2 = g0; i2 = 0; }
  if (i1 != 1 && g1 > b2) { b2 = g1; i2 = 1; }
  if (i1 != 2 && g2 > b2) { b2 = g2; i2 = 2; }
  if (i1 != 3 && g3 > b2) { b2 = g3; i2 = 3; }
  if (i1 != 4 && g4 > b2) { b2 = g4; i2 = 4; }
}

// ---------- gate helpers: 20-wide uniform W batch + fma ----------
__device__ __forceinline__ void ldw20(float* d, const float* __restrict__ p) {
#pragma unroll
  for (int j = 0; j < 20; ++j) d[j] = p[j];
}
__device__ __forceinline__ void fma20(float* acc, const float* wv, float xv) {
#pragma unroll
  for (int j = 0; j < 20; ++j) acc[j] = fmaf(xv, wv[j], acc[j]);
}

// ---------- fused gate GEMM v6 (exact fp32, 8-way in-tile K-split, Ws/Wd
// split across blockIdx.y) ----------
__global__ __launch_bounds__(1024) void gate_v6_kernel(
    const float* __restrict__ x, const float* __restrict__ Ws,
    const float* __restrict__ Wd, uint32_t* __restrict__ gsel32)
{
  __shared__ __align__(16) float xs[10752];   // 43,008 B; tiles use 64*132=8448
  int t = threadIdx.x;
  int m0 = blockIdx.x * 64;
  int g  = blockIdx.y;                         // 0 = Ws, 1 = Wd
  int w = t >> 6, lane = t & 63;
  int cg = __builtin_amdgcn_readfirstlane(w & 1);
  int kq = __builtin_amdgcn_readfirstlane(w >> 1);
  const float* __restrict__ Wg = g ? Wd : Ws;
  const float* __restrict__ wbase = Wg + (size_t)(kq * 16) * 40 + cg * 20;

  float acc[20];
#pragma unroll
  for (int j = 0; j < 20; ++j) acc[j] = 0.f;

  for (int tile = 0; tile < 8; ++tile) {
    __syncthreads();
    // stage x tile 64 rows x 128 k: float4 coalesced global, float4 LDS stores
#pragma unroll
    for (int rep = 0; rep < 2; ++rep) {
      int li = rep * 1024 + t;
      int row = li >> 5, kg = li & 31;
      float4 v = *(const float4*)&x[(size_t)(m0 + row) * 1024 + tile * 128 + kg * 4];
      *(float4*)&xs[row * 132 + kg * 4] = v;
    }
    __syncthreads();

    const float* wp = wbase + (size_t)tile * 128 * 40;
    const float* xp = &xs[lane * 132 + kq * 16];
    float wc[20], wn[20];
    ldw20(wc, wp);                       // k-local 0
#pragma unroll
    for (int k4 = 0; k4 < 4; ++k4) {     // 16 k per wave per tile
      float4 xv = *(const float4*)&xp[k4 * 4];
      ldw20(wn, wp + (size_t)(k4 * 4 + 1) * 40);
      fma20(acc, wc, xv.x);              // k = 4*k4+0
      ldw20(wc, wp + (size_t)(k4 * 4 + 2) * 40);
      fma20(acc, wn, xv.y);              // k = 4*k4+1
      ldw20(wn, wp + (size_t)(k4 * 4 + 3) * 40);
      fma20(acc, wc, xv.z);              // k = 4*k4+2
      if (k4 < 3) ldw20(wc, wp + (size_t)(k4 * 4 + 4) * 40);
      fma20(acc, wn, xv.w);              // k = 4*k4+3
    }
  }

  // ---- in-LDS 8-way K-split reduction, fixed tree, stride 21 ----
  float* red = xs;                       // reuse; 4 slots x 2 cg x 64 x 21
  __syncthreads();                       // xs (x tile) dead
  if (kq & 1) {                          // round 1 writers: kq 1,3,5,7
    int ro = (((kq >> 1) * 2 + cg) * 64 + lane) * 21;
#pragma unroll
    for (int j = 0; j < 20; ++j) red[ro + j] = acc[j];
  }
  __syncthreads();
  if (!(kq & 1)) {                       // round 1 readers: kq 0,2,4,6
    int ro = (((kq >> 1) * 2 + cg) * 64 + lane) * 21;
#pragma unroll
    for (int j = 0; j < 20; ++j) acc[j] += red[ro + j];
  }
  __syncthreads();
  if (kq == 2 || kq == 6) {              // round 2 writers
    int ro = (((kq >> 2) * 2 + cg) * 64 + lane) * 21;
#pragma unroll
    for (int j = 0; j < 20; ++j) red[ro + j] = acc[j];
  }
  __syncthreads();
  if (kq == 0 || kq == 4) {              // round 2 readers
    int ro = (((kq >> 2) * 2 + cg) * 64 + lane) * 21;
#pragma unroll
    for (int j = 0; j < 20; ++j) acc[j] += red[ro + j];
  }
  __syncthreads();
  if (kq == 4) {                         // round 3 writer
    int ro = (cg * 64 + lane) * 21;
#pragma unroll
    for (int j = 0; j < 20; ++j) red[ro + j] = acc[j];
  }
  __syncthreads();

  if (kq == 0) {
    int ro = (cg * 64 + lane) * 21;
#pragma unroll
    for (int j = 0; j < 20; ++j) acc[j] += red[ro + j];   // full sum
    int m = m0 + lane;
    if (g == 0) {      // Ws: V-expert selection + sigmoid weights (words 0-2)
#pragma unroll
      for (int hh = 0; hh < 4; ++hh) {
        int i1, i2; float b1, b2;
        top2_5(acc[hh * 5 + 0], acc[hh * 5 + 1], acc[hh * 5 + 2],
               acc[hh * 5 + 3], acc[hh * 5 + 4], i1, b1, i2, b2);
        float w1 = 1.f / (1.f + __expf(-b1));
        float w2 = 1.f / (1.f + __expf(-b2));
        uint32_t* gp = gsel32 + ((size_t)m * 8 + cg * 4 + hh) * 4;
        gp[0] = __float_as_uint(w1);
        gp[1] = __float_as_uint(w2);
        gp[2] = (uint32_t)(i1 | (i2 << 3));
      }
    } else {           // Wd: out-expert selection only (word 3)
#pragma unroll
      for (int hh = 0; hh < 4; ++hh) {
        int j1, j2; float c1, c2;
        top2_5(acc[hh * 5 + 0], acc[hh * 5 + 1], acc[hh * 5 + 2],
               acc[hh * 5 + 3], acc[hh * 5 + 4], j1, c1, j2, c2);
        uint32_t* gp = gsel32 + ((size_t)m * 8 + cg * 4 + hh) * 4;
        gp[3] = (uint32_t)(j1 | (j2 << 3));
      }
    }
  }
}

// ---------- proj MFMA GEMM (m97-style): global_load_lds into unpadded tiles ----------
__global__ __launch_bounds__(256) void proj_mfma_kernel(
    const uint16_t* __restrict__ xb, const uint16_t* __restrict__ Wt,
    uint16_t* __restrict__ proj)
{
  __shared__ __align__(16) uint16_t As[128 * 32];  // [m][k] unpadded (required by lds-DMA)
  __shared__ __align__(16) uint16_t Bs[128 * 32];  // [n][k]
  int t = threadIdx.x;
  int n0 = blockIdx.x * 128, m0 = blockIdx.y * 128;
  int w = t >> 6, lane = t & 63, q = lane >> 4, c = lane & 15;
  int wm = w & 1, wn = w >> 1;
  int lr = lane >> 2, lc = (lane & 3) * 8;   // 16 rows/chunk, 16B per lane
  f32x4 zf = {0.f, 0.f, 0.f, 0.f};
  f32x4 acc[4][4];
#pragma unroll
  for (int i = 0; i < 4; ++i)
#pragma unroll
    for (int j = 0; j < 4; ++j) acc[i][j] = zf;

  for (int kb = 0; kb < 32; ++kb) {
    __syncthreads();
#pragma unroll
    for (int j = 0; j < 2; ++j) {
      int row = w * 32 + j * 16 + lr;
      gload16(xb + (size_t)(m0 + row) * 1024 + kb * 32 + lc,
              &As[(w * 32 + j * 16) * 32 + lane * 8]);
      gload16(Wt + (size_t)(n0 + row) * 1024 + kb * 32 + lc,
              &Bs[(w * 32 + j * 16) * 32 + lane * 8]);
    }
    __syncthreads();
    short8 af[4], bfr[4];
#pragma unroll
    for (int i = 0; i < 4; ++i)
      af[i] = *(const short8*)&As[(wm * 64 + i * 16 + c) * 32 + q * 8];
#pragma unroll
    for (int j = 0; j < 4; ++j)
      bfr[j] = *(const short8*)&Bs[(wn * 64 + j * 16 + c) * 32 + q * 8];
#pragma unroll
    for (int i = 0; i < 4; ++i)
#pragma unroll
      for (int j = 0; j < 4; ++j)
        acc[i][j] = __builtin_amdgcn_mfma_f32_16x16x32_bf16(af[i], bfr[j], acc[i][j], 0, 0, 0);
  }
#pragma unroll
  for (int i = 0; i < 4; ++i)
#pragma unroll
    for (int j = 0; j < 4; ++j) {
      int col = n0 + wn * 64 + j * 16 + c;
      if (col < PLD) {
#pragma unroll
        for (int reg = 0; reg < 4; ++reg) {
          int row = m0 + wm * 64 + i * 16 + q * 4 + reg;
          proj[(size_t)row * PLD + col] = bfr1(acc[i][j][reg]);
        }
      }
    }
}

// ---------- out MFMA GEMM: zbuf[8192][320] @ WoT^T -> out fp32 [8192][1024] ----------
__global__ __launch_bounds__(256) void out_mfma_kernel(
    const uint16_t* __restrict__ zb, const uint16_t* __restrict__ WoT,
    float* __restrict__ out)
{
  __shared__ __align__(16) uint16_t As[128 * 32];
  __shared__ __align__(16) uint16_t Bs[128 * 32];
  int t = threadIdx.x;
  int n0 = blockIdx.x * 128, m0 = blockIdx.y * 128;
  int w = t >> 6, lane = t & 63, q = lane >> 4, c = lane & 15;
  int wm = w & 1, wn = w >> 1;
  int lr = lane >> 2, lc = (lane & 3) * 8;
  f32x4 zf = {0.f, 0.f, 0.f, 0.f};
  f32x4 acc[4][4];
#pragma unroll
  for (int i = 0; i < 4; ++i)
#pragma unroll
    for (int j = 0; j < 4; ++j) acc[i][j] = zf;

  for (int kb = 0; kb < 10; ++kb) {
    __syncthreads();
#pragma unroll
    for (int j = 0; j < 2; ++j) {
      int row = w * 32 + j * 16 + lr;
      gload16(zb + (size_t)(m0 + row) * 320 + kb * 32 + lc,
              &As[(w * 32 + j * 16) * 32 + lane * 8]);
      gload16(WoT + (size_t)(n0 + row) * 320 + kb * 32 + lc,
              &Bs[(w * 32 + j * 16) * 32 + lane * 8]);
    }
    __syncthreads();
    short8 af[4], bfr[4];
#pragma unroll
    for (int i = 0; i < 4; ++i)
      af[i] = *(const short8*)&As[(wm * 64 + i * 16 + c) * 32 + q * 8];
#pragma unroll
    for (int j = 0; j < 4; ++j)
      bfr[j] = *(const short8*)&Bs[(wn * 64 + j * 16 + c) * 32 + q * 8];
#pragma unroll
    for (int i = 0; i < 4; ++i)
#pragma unroll
      for (int j = 0; j < 4; ++j)
        acc[i][j] = __builtin_amdgcn_mfma_f32_16x16x32_bf16(af[i], bfr[j], acc[i][j], 0, 0, 0);
  }
#pragma unroll
  for (int i = 0; i < 4; ++i)
#pragma unroll
    for (int j = 0; j < 4; ++j) {
      int col = n0 + wn * 64 + j * 16 + c;
#pragma unroll
      for (int reg = 0; reg < 4; ++reg) {
        int row = m0 + wm * 64 + i * 16 + q * 4 + reg;
        out[(size_t)row * 1024 + col] = acc[i][j][reg];
      }
    }
}

// ---------- vbuild: v combine into d-major vt, TRUE j order (32x32 flash
// consumes V[j][d] via B-frag k = contiguous j) ----------
__global__ __launch_bounds__(256) void vbuild_kernel(
    const uint16_t* __restrict__ proj, const uint4* __restrict__ gsel,
    uint16_t* __restrict__ vt)
{
  int bi = blockIdx.x;            // 1024 = bh(32) x tb(32)
  int bh = bi >> 5, tb = bi & 31;
  int b = bh >> 3, h = bh & 7;
  int t = threadIdx.x;
  int tt = t & 63, dg = t >> 6;
  int m = b * 2048 + tb * 64 + tt;
  uint4 gs = gsel[m * 8 + h];
  float w1 = __uint_as_float(gs.x), w2 = __uint_as_float(gs.y);
  int i1 = gs.z & 7, i2 = (gs.z >> 3) & 7;
  const uint16_t* base = proj + (size_t)m * PLD + 1024;
  const uint4* p1 = (const uint4*)(base + i1 * 64 + dg * 16);
  const uint4* p2 = (const uint4*)(base + i2 * 64 + dg * 16);
  uint4 A0 = p1[0], A1 = p1[1], B0 = p2[0], B1 = p2[1];
  float v[16];
  v[0]  = w1*bflo(A0.x) + w2*bflo(B0.x); v[1]  = w1*bfhi(A0.x) + w2*bfhi(B0.x);
  v[2]  = w1*bflo(A0.y) + w2*bflo(B0.y); v[3]  = w1*bfhi(A0.y) + w2*bfhi(B0.y);
  v[4]  = w1*bflo(A0.z) + w2*bflo(B0.z); v[5]  = w1*bfhi(A0.z) + w2*bfhi(B0.z);
  v[6]  = w1*bflo(A0.w) + w2*bflo(B0.w); v[7]  = w1*bfhi(A0.w) + w2*bfhi(B0.w);
  v[8]  = w1*bflo(A1.x) + w2*bflo(B1.x); v[9]  = w1*bfhi(A1.x) + w2*bfhi(B1.x);
  v[10] = w1*bflo(A1.y) + w2*bflo(B1.y); v[11] = w1*bfhi(A1.y) + w2*bfhi(B1.y);
  v[12] = w1*bflo(A1.z) + w2*bflo(B1.z); v[13] = w1*bfhi(A1.z) + w2*bfhi(B1.z);
  v[14] = w1*bflo(A1.w) + w2*bflo(B1.w); v[15] = w1*bfhi(A1.w) + w2*bfhi(B1.w);
#pragma unroll
  for (int dd = 0; dd < 16; ++dd)
    vt[(size_t)(bh * 64 + dg * 16 + dd) * 2048 + tb * 64 + tt] = bfr1(v[dd]);
}

// ---------- flash attention v4: 32x32x16 MFMA, swapped QK^T, in-register P
// (T12), QBLK=64 x 2 waves (grid 1024 -> up to 8 blocks/CU, LDS 18.7KB),
// K/V register-prefetch, no-max softmax with folded 0.125 scale ----------
__global__ __launch_bounds__(128, 4) void flash_mfma_kernel(
    const uint16_t* __restrict__ proj, const uint16_t* __restrict__ vt,
    uint16_t* __restrict__ attnb)
{
  __shared__ __align__(16) uint16_t Ks[64 * 72];   // [j][d]
  __shared__ __align__(16) uint16_t Vs[64 * 72];   // [d][j] true-j order
  __shared__ float lsb[2 * 32];                    // per-wave 1/rowsum
  int t = threadIdx.x;
  int bx = blockIdx.x;
  int qb = bx & 31, bh = bx >> 5;
  int h = bh & 7, b = bh >> 3;
  int w = t >> 6, lane = t & 63;
  int r31 = lane & 31, hi = lane >> 5;
  int srow = t >> 1, scq = t & 1;                  // 2 threads/row, 32 cols each

  // Q B-fragments (persist): lane holds q-row r31 of this wave's 32-row group.
  short8 qf[4];
  {
    const uint16_t* qp = proj + (size_t)(b * 2048 + qb * 64 + w * 32 + r31) * PLD + h * 64 + hi * 8;
#pragma unroll
    for (int f = 0; f < 4; ++f) qf[f] = *(const short8*)(qp + 16 * f);
  }

  f32x16 o0 = {0.f}, o1 = {0.f};
#pragma unroll
  for (int i = 0; i < 16; ++i) { o0[i] = 0.f; o1[i] = 0.f; }
  float lsacc = 0.f;

  // K/V register prefetch: 4 uint4 each (32B-wide rows, 2 threads/row).
  const uint16_t* kg = proj + (size_t)(b * 2048 + srow) * PLD + 512 + h * 64 + scq * 32;
  const uint16_t* vg = vt + (size_t)(bh * 64 + srow) * 2048 + scq * 32;
  uint4 kp[4], vp[4];
#pragma unroll
  for (int j = 0; j < 4; ++j) { kp[j] = ((const uint4*)kg)[j]; vp[j] = ((const uint4*)vg)[j]; }

  for (int it = 0; it < 32; ++it) {
    if (it) __syncthreads();             // prev compute done reading Ks/Vs
#pragma unroll
    for (int j = 0; j < 4; ++j) {
      *(uint4*)&Ks[srow * 72 + scq * 32 + j * 8] = kp[j];
      *(uint4*)&Vs[srow * 72 + scq * 32 + j * 8] = vp[j];
    }
    __syncthreads();
    if (it < 31) {                       // overlap next-tile loads with compute
      const uint4* pk = (const uint4*)(kg + (size_t)(it + 1) * 64 * PLD);
      const uint4* pv = (const uint4*)(vg + (it + 1) * 64);
#pragma unroll
      for (int j = 0; j < 4; ++j) { kp[j] = pk[j]; vp[j] = pv[j]; }
    }

    // Per j-group (32 K-rows): S^T = mfma(A=K, B=Q); C col = r (lane-local
    // q-row), C row j = (reg&3) + 8*(reg>>2) + 4*hi. Then P in-register.
    short8 pa[4];
#pragma unroll
    for (int jg = 0; jg < 2; ++jg) {
      f32x16 s;
#pragma unroll
      for (int i = 0; i < 16; ++i) s[i] = 0.f;
#pragma unroll
      for (int f = 0; f < 4; ++f) {
        short8 kf = *(const short8*)&Ks[(jg * 32 + r31) * 72 + hi * 8 + 16 * f];
        s = __builtin_amdgcn_mfma_f32_32x32x16_bf16(kf, qf[f], s, 0, 0, 0);
      }
      float p[16];
#pragma unroll
      for (int reg = 0; reg < 16; ++reg)
        p[reg] = __builtin_amdgcn_exp2f(s[reg] * 0.18033688f);
      lsacc += (((p[0] + p[1]) + (p[2] + p[3])) + ((p[4] + p[5]) + (p[6] + p[7])))
             + (((p[8] + p[9]) + (p[10] + p[11])) + ((p[12] + p[13]) + (p[14] + p[15])));
      // cvt_pk adjacent-j pairs, then permlane32_swap to assemble PV A-frags
      uint32_t X1 = cvtpk(p[0], p[1]),  X2 = cvtpk(p[2], p[3]);
      uint32_t Y1 = cvtpk(p[4], p[5]),  Y2 = cvtpk(p[6], p[7]);
      uint32_t Z1 = cvtpk(p[8], p[9]),  Z2 = cvtpk(p[10], p[11]);
      uint32_t W1 = cvtpk(p[12], p[13]), W2 = cvtpk(p[14], p[15]);
      u32x2 s1 = __builtin_amdgcn_permlane32_swap(X1, Y1, false, false);
      u32x2 s2 = __builtin_amdgcn_permlane32_swap(X2, Y2, false, false);
      u32x2 s3 = __builtin_amdgcn_permlane32_swap(Z1, W1, false, false);
      u32x2 s4 = __builtin_amdgcn_permlane32_swap(Z2, W2, false, false);
      uint4 f0 = { s1.x, s2.x, s1.y, s2.y };   // j = jg*32 + hi*8 + 0..7
      uint4 f1 = { s3.x, s4.x, s3.y, s4.y };   // j = jg*32 + 16 + hi*8 + 0..7
      pa[jg * 2 + 0] = *(short8*)&f0;
      pa[jg * 2 + 1] = *(short8*)&f1;
    }

    // O += P V : per d-tile, 4 mfma over j=64; B=V from d-major Vs (true j).
#pragma unroll
    for (int f = 0; f < 4; ++f) {
      short8 vf0 = *(const short8*)&Vs[(r31) * 72 + hi * 8 + 16 * f];
      short8 vf1 = *(const short8*)&Vs[(32 + r31) * 72 + hi * 8 + 16 * f];
      o0 = __builtin_amdgcn_mfma_f32_32x32x16_bf16(pa[f], vf0, o0, 0, 0, 0);
      o1 = __builtin_amdgcn_mfma_f32_32x32x16_bf16(pa[f], vf1, o1, 0, 0, 0);
    }
  }

  // row sums: lane-local partial + partner half; broadcast 1/ls via wave-
  // private LDS (same-wave DS ordering, no barrier needed).
  float lsc = lsacc + __shfl_xor(lsacc, 32);
  if (lane < 32) lsb[w * 32 + r31] = 1.0f / lsc;
#pragma unroll
  for (int reg = 0; reg < 16; ++reg) {
    int r = (reg & 3) + 8 * (reg >> 2) + 4 * hi;
    float inv = lsb[w * 32 + r];
    size_t row = (size_t)(b * 2048 + qb * 64 + w * 32 + r);
    attnb[row * 512 + h * 64 + r31]      = bfr1(o0[reg] * inv);
    attnb[row * 512 + h * 64 + 32 + r31] = bfr1(o1[reg] * inv);
  }
}

// ---------- zbuild: z[m][e*64+c] = sum_h mask_o[h,e] * attn[m][h*64+c] ----------
__global__ __launch_bounds__(64) void zbuild_kernel(
    const uint16_t* __restrict__ attnb, const uint32_t* __restrict__ gselw,
    uint16_t* __restrict__ zbuf)
{
  int m = blockIdx.x; int c = threadIdx.x;
  float acc[5] = {0.f, 0.f, 0.f, 0.f, 0.f};
#pragma unroll
  for (int h = 0; h < 8; ++h) {
    uint32_t sel = gselw[(m * 8 + h) * 4 + 3];
    int e1 = sel & 7, e2 = (sel >> 3) & 7;
    float a = bf2f(attnb[(size_t)m * 512 + h * 64 + c]);
#pragma unroll
    for (int e = 0; e < 5; ++e)
      acc[e] += (e == e1 || e == e2) ? a : 0.f;
  }
#pragma unroll
  for (int e = 0; e < 5; ++e)
    zbuf[(size_t)m * 320 + e * 64 + c] = bfr1(acc[e]);
}

// ---------- launch ----------
extern "C" void kernel_launch(void* const* d_in, const int* in_sizes, int n_in,
                              void* d_out, int out_size, void* d_ws, size_t ws_size,
                              hipStream_t stream) {
  const float* x  = (const float*)d_in[0];
  const float* Wq = (const float*)d_in[1];
  const float* Wk = (const float*)d_in[2];
  const float* Ws = (const float*)d_in[3];
  const float* Wd = (const float*)d_in[4];
  const float* Wv = (const float*)d_in[5];
  const float* Wo = (const float*)d_in[6];
  float* out = (float*)d_out;

  // workspace carve, lifetime-aliased; high-water 51,773,440 B
  char* ws = (char*)d_ws;
  uint4*    gsel  = (uint4*)   (ws);                  // [0, 1,048,576)
  uint16_t* WoT   = (uint16_t*)(ws + 1048576);        // [.., 1,703,936)
  uint16_t* Wt    = (uint16_t*)(ws + 1703936);        // [.., 4,587,520)  dead after proj
  uint16_t* xb    = (uint16_t*)(ws + 4587520);        // [.., 21,364,736) dead after proj
  uint16_t* proj  = (uint16_t*)(ws + 21364736);       // [.., 43,384,832)
  uint16_t* vt    = (uint16_t*)(ws + 43384832);       // [.., 51,773,440)
  uint16_t* attnb = (uint16_t*)(ws + 1703936);        // alias Wt+xb (dead)
  uint16_t* zbuf  = (uint16_t*)(ws + 10092544);       // alias xb tail

  gate_v6_kernel<<<dim3(MM / 64, 2), 1024, 0, stream>>>(x, Ws, Wd, (uint32_t*)gsel);
  pack_wt_kernel<<<dim3(16, 22), 256, 0, stream>>>(Wq, Wk, Wv, Wt);
  pack_wot_kernel<<<dim3(5, 16), 256, 0, stream>>>(Wo, WoT);
  xbf_kernel<<<(MM * DD / 4) / 256, 256, 0, stream>>>(x, xb);
  proj_mfma_kernel<<<dim3(NWT / 128, MM / 128), 256, 0, stream>>>(xb, Wt, proj);
  vbuild_kernel<<<32 * 32, 256, 0, stream>>>(proj, gsel, vt);
  flash_mfma_kernel<<<BB * HH * (TT / 64), 128, 0, stream>>>(proj, vt, attnb);
  zbuild_kernel<<<MM, 64, 0, stream>>>(attnb, (const uint32_t*)gsel, zbuf);
  out_mfma_kernel<<<dim3(DD / 128, MM / 128), 256, 0, stream>>>(zbuf, WoT, out);
}

// Round 8
// 236.540 us; speedup vs baseline: 1.4394x; 1.4394x over previous
//
#include <hip/hip_runtime.h>
#include <cstdint>
#include <cstddef>

// Problem constants
#define BB 4
#define TT 2048
#define DD 1024
#define HH 8
#define DH 64
#define EE 5
#define MM (BB*TT)          // 8192 rows
#define PLD 1344            // proj leading dim (q 512 | k 512 | xv 320)
#define NWT 1408            // padded N for MFMA proj (11 * 128)

typedef short short8 __attribute__((ext_vector_type(8)));
typedef float f32x4  __attribute__((ext_vector_type(4)));
typedef float f32x16 __attribute__((ext_vector_type(16)));
typedef unsigned int u32x2 __attribute__((ext_vector_type(2)));

// ---------- bf16 helpers ----------
__device__ __forceinline__ float bflo(uint32_t u) { union { uint32_t i; float f; } v; v.i = u << 16; return v.f; }
__device__ __forceinline__ float bfhi(uint32_t u) { union { uint32_t i; float f; } v; v.i = u & 0xFFFF0000u; return v.f; }
__device__ __forceinline__ float bf2f(uint16_t u) { union { uint32_t i; float f; } v; v.i = ((uint32_t)u) << 16; return v.f; }
// cheap bf16 pack: round-half-up (+0x8000) then v_perm_b32 pair-pack (1 op).
__device__ __forceinline__ uint32_t pkbf(float a, float b) {
  uint32_t ua = __float_as_uint(a) + 0x8000u;
  uint32_t ub = __float_as_uint(b) + 0x8000u;
  return __builtin_amdgcn_perm(ub, ua, 0x07060302u);  // [ua.b2,ua.b3,ub.b2,ub.b3]
}
__device__ __forceinline__ uint16_t bfr1(float f) {
  return (uint16_t)((__float_as_uint(f) + 0x8000u) >> 16);
}
// RNE pair-pack via hardware cvt (1 op); lo = a, hi = b
__device__ __forceinline__ uint32_t cvtpk(float a, float b) {
  uint32_t r;
  asm("v_cvt_pk_bf16_f32 %0, %1, %2" : "=v"(r) : "v"(a), "v"(b));
  return r;
}

// ---------- async global->LDS, 16B per lane (dest = wave base + lane*16) ----------
__device__ __forceinline__ void gload16(const void* g, void* l) {
  __builtin_amdgcn_global_load_lds(
      (const __attribute__((address_space(1))) uint32_t*)g,
      (__attribute__((address_space(3))) uint32_t*)l, 16, 0, 0);
}

// ---------- pack W^T bf16 [NWT][1024] for MFMA proj (LDS tile transpose) ----------
__global__ __launch_bounds__(256) void pack_wt_kernel(
    const float* __restrict__ Wq, const float* __restrict__ Wk,
    const float* __restrict__ Wv, uint16_t* __restrict__ Wt)
{
  __shared__ __align__(16) uint16_t Ts[64 * 68];
  int k0 = blockIdx.x * 64, n0 = blockIdx.y * 64;
  int t = threadIdx.x;
#pragma unroll
  for (int rep = 0; rep < 16; ++rep) {
    int li = rep * 256 + t;
    int kl = li >> 6, nl = li & 63;
    int k = k0 + kl, n = n0 + nl;
    float v = 0.f;
    if (n < 512)       v = Wq[k * 512 + n];
    else if (n < 1024) v = Wk[k * 512 + (n - 512)];
    else if (n < 1344) { int nn = n - 1024; v = Wv[((size_t)(nn >> 6) * 1024 + k) * 64 + (nn & 63)]; }
    Ts[kl * 68 + nl] = bfr1(v);
  }
  __syncthreads();
#pragma unroll
  for (int rep = 0; rep < 16; ++rep) {
    int li = rep * 256 + t;
    int nl = li >> 6, kl = li & 63;
    Wt[(size_t)(n0 + nl) * 1024 + k0 + kl] = Ts[kl * 68 + nl];
  }
}

// ---------- pack Wo[320][1024] fp32 -> WoT bf16 [1024][320] ----------
__global__ __launch_bounds__(256) void pack_wot_kernel(
    const float* __restrict__ Wo, uint16_t* __restrict__ WoT)
{
  __shared__ __align__(16) uint16_t Ts[64 * 68];
  int k0 = blockIdx.x * 64, n0 = blockIdx.y * 64;
  int t = threadIdx.x;
#pragma unroll
  for (int rep = 0; rep < 16; ++rep) {
    int li = rep * 256 + t;
    int kl = li >> 6, nl = li & 63;
    Ts[kl * 68 + nl] = bfr1(Wo[(size_t)(k0 + kl) * 1024 + n0 + nl]);
  }
  __syncthreads();
#pragma unroll
  for (int rep = 0; rep < 16; ++rep) {
    int li = rep * 256 + t;
    int nl = li >> 6, kl = li & 63;
    WoT[(size_t)(n0 + nl) * 320 + k0 + kl] = Ts[kl * 68 + nl];
  }
}

// ---------- x -> bf16 ----------
__global__ __launch_bounds__(256) void xbf_kernel(const float* __restrict__ x, uint16_t* __restrict__ xb)
{
  int i = (blockIdx.x * 256 + threadIdx.x) * 4;
  float4 v = *(const float4*)(x + i);
  uint2 o;
  o.x = pkbf(v.x, v.y);
  o.y = pkbf(v.z, v.w);
  *(uint2*)(xb + i) = o;
}

// ---------- top-2 of 5 (lax.top_k tie rule: lower index wins) ----------
__device__ __forceinline__ void top2_5(float g0, float g1, float g2, float g3, float g4,
                                       int& i1, float& b1, int& i2, float& b2) {
  i1 = 0; b1 = g0;
  if (g1 > b1) { b1 = g1; i1 = 1; }
  if (g2 > b1) { b1 = g2; i1 = 2; }
  if (g3 > b1) { b1 = g3; i1 = 3; }
  if (g4 > b1) { b1 = g4; i1 = 4; }
  i2 = -1; b2 = -__builtin_inff();
  if (i1 != 0 && g0 > b2) { b2 = g0; i2 = 0; }
  if (i1 != 1 && g1 > b2) { b2 = g1; i2 = 1; }
  if (i1 != 2 && g2 > b2) { b2 = g2; i2 = 2; }
  if (i1 != 3 && g3 > b2) { b2 = g3; i2 = 3; }
  if (i1 != 4 && g4 > b2) { b2 = g4; i2 = 4; }
}

// ---------- gate helpers: 20-wide uniform W batch + fma ----------
__device__ __forceinline__ void ldw20(float* d, const float* __restrict__ p) {
#pragma unroll
  for (int j = 0; j < 20; ++j) d[j] = p[j];
}
__device__ __forceinline__ void fma20(float* acc, const float* wv, float xv) {
#pragma unroll
  for (int j = 0; j < 20; ++j) acc[j] = fmaf(xv, wv[j], acc[j]);
}

// ---------- fused gate GEMM v6 (exact fp32, 8-way in-tile K-split, Ws/Wd
// split across blockIdx.y) ----------
__global__ __launch_bounds__(1024) void gate_v6_kernel(
    const float* __restrict__ x, const float* __restrict__ Ws,
    const float* __restrict__ Wd, uint32_t* __restrict__ gsel32)
{
  __shared__ __align__(16) float xs[10752];   // 43,008 B; tiles use 64*132=8448
  int t = threadIdx.x;
  int m0 = blockIdx.x * 64;
  int g  = blockIdx.y;                         // 0 = Ws, 1 = Wd
  int w = t >> 6, lane = t & 63;
  int cg = __builtin_amdgcn_readfirstlane(w & 1);
  int kq = __builtin_amdgcn_readfirstlane(w >> 1);
  const float* __restrict__ Wg = g ? Wd : Ws;
  const float* __restrict__ wbase = Wg + (size_t)(kq * 16) * 40 + cg * 20;

  float acc[20];
#pragma unroll
  for (int j = 0; j < 20; ++j) acc[j] = 0.f;

  for (int tile = 0; tile < 8; ++tile) {
    __syncthreads();
    // stage x tile 64 rows x 128 k: float4 coalesced global, float4 LDS stores
#pragma unroll
    for (int rep = 0; rep < 2; ++rep) {
      int li = rep * 1024 + t;
      int row = li >> 5, kg = li & 31;
      float4 v = *(const float4*)&x[(size_t)(m0 + row) * 1024 + tile * 128 + kg * 4];
      *(float4*)&xs[row * 132 + kg * 4] = v;
    }
    __syncthreads();

    const float* wp = wbase + (size_t)tile * 128 * 40;
    const float* xp = &xs[lane * 132 + kq * 16];
    float wc[20], wn[20];
    ldw20(wc, wp);                       // k-local 0
#pragma unroll
    for (int k4 = 0; k4 < 4; ++k4) {     // 16 k per wave per tile
      float4 xv = *(const float4*)&xp[k4 * 4];
      ldw20(wn, wp + (size_t)(k4 * 4 + 1) * 40);
      fma20(acc, wc, xv.x);              // k = 4*k4+0
      ldw20(wc, wp + (size_t)(k4 * 4 + 2) * 40);
      fma20(acc, wn, xv.y);              // k = 4*k4+1
      ldw20(wn, wp + (size_t)(k4 * 4 + 3) * 40);
      fma20(acc, wc, xv.z);              // k = 4*k4+2
      if (k4 < 3) ldw20(wc, wp + (size_t)(k4 * 4 + 4) * 40);
      fma20(acc, wn, xv.w);              // k = 4*k4+3
    }
  }

  // ---- in-LDS 8-way K-split reduction, fixed tree, stride 21 ----
  float* red = xs;                       // reuse; 4 slots x 2 cg x 64 x 21
  __syncthreads();                       // xs (x tile) dead
  if (kq & 1) {                          // round 1 writers: kq 1,3,5,7
    int ro = (((kq >> 1) * 2 + cg) * 64 + lane) * 21;
#pragma unroll
    for (int j = 0; j < 20; ++j) red[ro + j] = acc[j];
  }
  __syncthreads();
  if (!(kq & 1)) {                       // round 1 readers: kq 0,2,4,6
    int ro = (((kq >> 1) * 2 + cg) * 64 + lane) * 21;
#pragma unroll
    for (int j = 0; j < 20; ++j) acc[j] += red[ro + j];
  }
  __syncthreads();
  if (kq == 2 || kq == 6) {              // round 2 writers
    int ro = (((kq >> 2) * 2 + cg) * 64 + lane) * 21;
#pragma unroll
    for (int j = 0; j < 20; ++j) red[ro + j] = acc[j];
  }
  __syncthreads();
  if (kq == 0 || kq == 4) {              // round 2 readers
    int ro = (((kq >> 2) * 2 + cg) * 64 + lane) * 21;
#pragma unroll
    for (int j = 0; j < 20; ++j) acc[j] += red[ro + j];
  }
  __syncthreads();
  if (kq == 4) {                         // round 3 writer
    int ro = (cg * 64 + lane) * 21;
#pragma unroll
    for (int j = 0; j < 20; ++j) red[ro + j] = acc[j];
  }
  __syncthreads();

  if (kq == 0) {
    int ro = (cg * 64 + lane) * 21;
#pragma unroll
    for (int j = 0; j < 20; ++j) acc[j] += red[ro + j];   // full sum
    int m = m0 + lane;
    if (g == 0) {      // Ws: V-expert selection + sigmoid weights (words 0-2)
#pragma unroll
      for (int hh = 0; hh < 4; ++hh) {
        int i1, i2; float b1, b2;
        top2_5(acc[hh * 5 + 0], acc[hh * 5 + 1], acc[hh * 5 + 2],
               acc[hh * 5 + 3], acc[hh * 5 + 4], i1, b1, i2, b2);
        float w1 = 1.f / (1.f + __expf(-b1));
        float w2 = 1.f / (1.f + __expf(-b2));
        uint32_t* gp = gsel32 + ((size_t)m * 8 + cg * 4 + hh) * 4;
        gp[0] = __float_as_uint(w1);
        gp[1] = __float_as_uint(w2);
        gp[2] = (uint32_t)(i1 | (i2 << 3));
      }
    } else {           // Wd: out-expert selection only (word 3)
#pragma unroll
      for (int hh = 0; hh < 4; ++hh) {
        int j1, j2; float c1, c2;
        top2_5(acc[hh * 5 + 0], acc[hh * 5 + 1], acc[hh * 5 + 2],
               acc[hh * 5 + 3], acc[hh * 5 + 4], j1, c1, j2, c2);
        uint32_t* gp = gsel32 + ((size_t)m * 8 + cg * 4 + hh) * 4;
        gp[3] = (uint32_t)(j1 | (j2 << 3));
      }
    }
  }
}

// ---------- proj MFMA GEMM (m97-style): global_load_lds into unpadded tiles ----------
__global__ __launch_bounds__(256) void proj_mfma_kernel(
    const uint16_t* __restrict__ xb, const uint16_t* __restrict__ Wt,
    uint16_t* __restrict__ proj)
{
  __shared__ __align__(16) uint16_t As[128 * 32];  // [m][k] unpadded (required by lds-DMA)
  __shared__ __align__(16) uint16_t Bs[128 * 32];  // [n][k]
  int t = threadIdx.x;
  int n0 = blockIdx.x * 128, m0 = blockIdx.y * 128;
  int w = t >> 6, lane = t & 63, q = lane >> 4, c = lane & 15;
  int wm = w & 1, wn = w >> 1;
  int lr = lane >> 2, lc = (lane & 3) * 8;   // 16 rows/chunk, 16B per lane
  f32x4 zf = {0.f, 0.f, 0.f, 0.f};
  f32x4 acc[4][4];
#pragma unroll
  for (int i = 0; i < 4; ++i)
#pragma unroll
    for (int j = 0; j < 4; ++j) acc[i][j] = zf;

  for (int kb = 0; kb < 32; ++kb) {
    __syncthreads();
#pragma unroll
    for (int j = 0; j < 2; ++j) {
      int row = w * 32 + j * 16 + lr;
      gload16(xb + (size_t)(m0 + row) * 1024 + kb * 32 + lc,
              &As[(w * 32 + j * 16) * 32 + lane * 8]);
      gload16(Wt + (size_t)(n0 + row) * 1024 + kb * 32 + lc,
              &Bs[(w * 32 + j * 16) * 32 + lane * 8]);
    }
    __syncthreads();
    short8 af[4], bfr[4];
#pragma unroll
    for (int i = 0; i < 4; ++i)
      af[i] = *(const short8*)&As[(wm * 64 + i * 16 + c) * 32 + q * 8];
#pragma unroll
    for (int j = 0; j < 4; ++j)
      bfr[j] = *(const short8*)&Bs[(wn * 64 + j * 16 + c) * 32 + q * 8];
#pragma unroll
    for (int i = 0; i < 4; ++i)
#pragma unroll
      for (int j = 0; j < 4; ++j)
        acc[i][j] = __builtin_amdgcn_mfma_f32_16x16x32_bf16(af[i], bfr[j], acc[i][j], 0, 0, 0);
  }
#pragma unroll
  for (int i = 0; i < 4; ++i)
#pragma unroll
    for (int j = 0; j < 4; ++j) {
      int col = n0 + wn * 64 + j * 16 + c;
      if (col < PLD) {
#pragma unroll
        for (int reg = 0; reg < 4; ++reg) {
          int row = m0 + wm * 64 + i * 16 + q * 4 + reg;
          proj[(size_t)row * PLD + col] = bfr1(acc[i][j][reg]);
        }
      }
    }
}

// ---------- out MFMA GEMM: zbuf[8192][320] @ WoT^T -> out fp32 [8192][1024] ----------
__global__ __launch_bounds__(256) void out_mfma_kernel(
    const uint16_t* __restrict__ zb, const uint16_t* __restrict__ WoT,
    float* __restrict__ out)
{
  __shared__ __align__(16) uint16_t As[128 * 32];
  __shared__ __align__(16) uint16_t Bs[128 * 32];
  int t = threadIdx.x;
  int n0 = blockIdx.x * 128, m0 = blockIdx.y * 128;
  int w = t >> 6, lane = t & 63, q = lane >> 4, c = lane & 15;
  int wm = w & 1, wn = w >> 1;
  int lr = lane >> 2, lc = (lane & 3) * 8;
  f32x4 zf = {0.f, 0.f, 0.f, 0.f};
  f32x4 acc[4][4];
#pragma unroll
  for (int i = 0; i < 4; ++i)
#pragma unroll
    for (int j = 0; j < 4; ++j) acc[i][j] = zf;

  for (int kb = 0; kb < 10; ++kb) {
    __syncthreads();
#pragma unroll
    for (int j = 0; j < 2; ++j) {
      int row = w * 32 + j * 16 + lr;
      gload16(zb + (size_t)(m0 + row) * 320 + kb * 32 + lc,
              &As[(w * 32 + j * 16) * 32 + lane * 8]);
      gload16(WoT + (size_t)(n0 + row) * 320 + kb * 32 + lc,
              &Bs[(w * 32 + j * 16) * 32 + lane * 8]);
    }
    __syncthreads();
    short8 af[4], bfr[4];
#pragma unroll
    for (int i = 0; i < 4; ++i)
      af[i] = *(const short8*)&As[(wm * 64 + i * 16 + c) * 32 + q * 8];
#pragma unroll
    for (int j = 0; j < 4; ++j)
      bfr[j] = *(const short8*)&Bs[(wn * 64 + j * 16 + c) * 32 + q * 8];
#pragma unroll
    for (int i = 0; i < 4; ++i)
#pragma unroll
      for (int j = 0; j < 4; ++j)
        acc[i][j] = __builtin_amdgcn_mfma_f32_16x16x32_bf16(af[i], bfr[j], acc[i][j], 0, 0, 0);
  }
#pragma unroll
  for (int i = 0; i < 4; ++i)
#pragma unroll
    for (int j = 0; j < 4; ++j) {
      int col = n0 + wn * 64 + j * 16 + c;
#pragma unroll
      for (int reg = 0; reg < 4; ++reg) {
        int row = m0 + wm * 64 + i * 16 + q * 4 + reg;
        out[(size_t)row * 1024 + col] = acc[i][j][reg];
      }
    }
}

// ---------- vbuild: v combine into d-major vt, TRUE j order (32x32 flash
// consumes V[j][d] via B-frag k = contiguous j) ----------
__global__ __launch_bounds__(256) void vbuild_kernel(
    const uint16_t* __restrict__ proj, const uint4* __restrict__ gsel,
    uint16_t* __restrict__ vt)
{
  int bi = blockIdx.x;            // 1024 = bh(32) x tb(32)
  int bh = bi >> 5, tb = bi & 31;
  int b = bh >> 3, h = bh & 7;
  int t = threadIdx.x;
  int tt = t & 63, dg = t >> 6;
  int m = b * 2048 + tb * 64 + tt;
  uint4 gs = gsel[m * 8 + h];
  float w1 = __uint_as_float(gs.x), w2 = __uint_as_float(gs.y);
  int i1 = gs.z & 7, i2 = (gs.z >> 3) & 7;
  const uint16_t* base = proj + (size_t)m * PLD + 1024;
  const uint4* p1 = (const uint4*)(base + i1 * 64 + dg * 16);
  const uint4* p2 = (const uint4*)(base + i2 * 64 + dg * 16);
  uint4 A0 = p1[0], A1 = p1[1], B0 = p2[0], B1 = p2[1];
  float v[16];
  v[0]  = w1*bflo(A0.x) + w2*bflo(B0.x); v[1]  = w1*bfhi(A0.x) + w2*bfhi(B0.x);
  v[2]  = w1*bflo(A0.y) + w2*bflo(B0.y); v[3]  = w1*bfhi(A0.y) + w2*bfhi(B0.y);
  v[4]  = w1*bflo(A0.z) + w2*bflo(B0.z); v[5]  = w1*bfhi(A0.z) + w2*bfhi(B0.z);
  v[6]  = w1*bflo(A0.w) + w2*bflo(B0.w); v[7]  = w1*bfhi(A0.w) + w2*bfhi(B0.w);
  v[8]  = w1*bflo(A1.x) + w2*bflo(B1.x); v[9]  = w1*bfhi(A1.x) + w2*bfhi(B1.x);
  v[10] = w1*bflo(A1.y) + w2*bflo(B1.y); v[11] = w1*bfhi(A1.y) + w2*bfhi(B1.y);
  v[12] = w1*bflo(A1.z) + w2*bflo(B1.z); v[13] = w1*bfhi(A1.z) + w2*bfhi(B1.z);
  v[14] = w1*bflo(A1.w) + w2*bflo(B1.w); v[15] = w1*bfhi(A1.w) + w2*bfhi(B1.w);
#pragma unroll
  for (int dd = 0; dd < 16; ++dd)
    vt[(size_t)(bh * 64 + dg * 16 + dd) * 2048 + tb * 64 + tt] = bfr1(v[dd]);
}

// ---------- flash attention v5: 32x32x16 MFMA, swapped QK^T, in-register P
// (T12), QBLK=128 x 8 waves = 2 KV-split groups x 4 waves. Group g handles
// KV tiles [g*16, g*16+16); no-max softmax is LINEAR in j so partial O/ls
// just add (fixed A+B order, deterministic). 2 blocks/CU x 8 waves = 4
// waves/SIMD (vs v3's 2). No launch_bounds VGPR clamp (round-7 spill lesson).
__global__ __launch_bounds__(512) void flash_mfma_kernel(
    const uint16_t* __restrict__ proj, const uint16_t* __restrict__ vt,
    uint16_t* __restrict__ attnb)
{
  // carve: K_g0 | K_g1 | V_g0 | V_g1 (each 64x72 bf16 = 9216 B) = 36,864 B.
  // Epilogue reuses [0,33792) as fp32 o-exchange, [33792,34304) ls-exchange,
  // [34304,34816) 1/ls broadcast.
  __shared__ __align__(16) char smem[36864];
  int t = threadIdx.x;
  int bx = blockIdx.x;
  int qb = bx & 15, bh = bx >> 4;
  int h = bh & 7, b = bh >> 3;
  int g = t >> 8;                          // KV-split group
  int tg = t & 255;                        // thread within group
  int w = t >> 6, wl = w & 3;              // wave, wave-within-group
  int lane = t & 63;
  int r31 = lane & 31, hi = lane >> 5;
  int srow = tg >> 2, scq = tg & 3;

  uint16_t* Ksg = (uint16_t*)smem + g * 4608;          // 64*72 halfwords
  uint16_t* Vsg = (uint16_t*)smem + 9216 + g * 4608;

  // Q B-fragments (persist): lane holds q-row r31 of this wave's 32-row group.
  short8 qf[4];
  {
    const uint16_t* qp = proj + (size_t)(b * 2048 + qb * 128 + wl * 32 + r31) * PLD + h * 64 + hi * 8;
#pragma unroll
    for (int f = 0; f < 4; ++f) qf[f] = *(const short8*)(qp + 16 * f);
  }

  f32x16 o0 = {0.f}, o1 = {0.f};
#pragma unroll
  for (int i = 0; i < 16; ++i) { o0[i] = 0.f; o1[i] = 0.f; }
  float lsacc = 0.f;

  // K/V register prefetch; group g covers KV rows [g*1024, g*1024+1024).
  const uint16_t* kg = proj + (size_t)(b * 2048 + g * 1024 + srow) * PLD + 512 + h * 64 + scq * 16;
  const uint16_t* vg = vt + (size_t)(bh * 64 + srow) * 2048 + g * 1024 + scq * 16;
  uint4 kp0, kp1, vp0, vp1;
  kp0 = ((const uint4*)kg)[0]; kp1 = ((const uint4*)kg)[1];
  vp0 = ((const uint4*)vg)[0]; vp1 = ((const uint4*)vg)[1];

  for (int it = 0; it < 16; ++it) {
    if (it) __syncthreads();             // prev compute done reading Ks/Vs
    *(uint4*)&Ksg[srow * 72 + scq * 16] = kp0;
    *(uint4*)&Ksg[srow * 72 + scq * 16 + 8] = kp1;
    *(uint4*)&Vsg[srow * 72 + scq * 16] = vp0;
    *(uint4*)&Vsg[srow * 72 + scq * 16 + 8] = vp1;
    __syncthreads();
    if (it < 15) {                       // overlap next-tile loads with compute
      const uint4* pk = (const uint4*)(kg + (size_t)(it + 1) * 64 * PLD);
      kp0 = pk[0]; kp1 = pk[1];
      const uint4* pv = (const uint4*)(vg + (it + 1) * 64);
      vp0 = pv[0]; vp1 = pv[1];
    }

    // Per j-group (32 K-rows): S^T = mfma(A=K, B=Q); C col = r (lane-local
    // q-row), C row j = (reg&3) + 8*(reg>>2) + 4*hi. Then P in-register.
    short8 pa[4];
#pragma unroll
    for (int jg = 0; jg < 2; ++jg) {
      f32x16 s;
#pragma unroll
      for (int i = 0; i < 16; ++i) s[i] = 0.f;
#pragma unroll
      for (int f = 0; f < 4; ++f) {
        short8 kf = *(const short8*)&Ksg[(jg * 32 + r31) * 72 + hi * 8 + 16 * f];
        s = __builtin_amdgcn_mfma_f32_32x32x16_bf16(kf, qf[f], s, 0, 0, 0);
      }
      float p[16];
#pragma unroll
      for (int reg = 0; reg < 16; ++reg)
        p[reg] = __builtin_amdgcn_exp2f(s[reg] * 0.18033688f);
      lsacc += (((p[0] + p[1]) + (p[2] + p[3])) + ((p[4] + p[5]) + (p[6] + p[7])))
             + (((p[8] + p[9]) + (p[10] + p[11])) + ((p[12] + p[13]) + (p[14] + p[15])));
      // cvt_pk adjacent-j pairs, then permlane32_swap to assemble PV A-frags
      uint32_t X1 = cvtpk(p[0], p[1]),  X2 = cvtpk(p[2], p[3]);
      uint32_t Y1 = cvtpk(p[4], p[5]),  Y2 = cvtpk(p[6], p[7]);
      uint32_t Z1 = cvtpk(p[8], p[9]),  Z2 = cvtpk(p[10], p[11]);
      uint32_t W1 = cvtpk(p[12], p[13]), W2 = cvtpk(p[14], p[15]);
      u32x2 s1 = __builtin_amdgcn_permlane32_swap(X1, Y1, false, false);
      u32x2 s2 = __builtin_amdgcn_permlane32_swap(X2, Y2, false, false);
      u32x2 s3 = __builtin_amdgcn_permlane32_swap(Z1, W1, false, false);
      u32x2 s4 = __builtin_amdgcn_permlane32_swap(Z2, W2, false, false);
      uint4 f0 = { s1.x, s2.x, s1.y, s2.y };   // j = jg*32 + hi*8 + 0..7
      uint4 f1 = { s3.x, s4.x, s3.y, s4.y };   // j = jg*32 + 16 + hi*8 + 0..7
      pa[jg * 2 + 0] = *(short8*)&f0;
      pa[jg * 2 + 1] = *(short8*)&f1;
    }

    // O += P V : per d-tile, 4 mfma over j=64; B=V from d-major Vs (true j).
#pragma unroll
    for (int f = 0; f < 4; ++f) {
      short8 vf0 = *(const short8*)&Vsg[(r31) * 72 + hi * 8 + 16 * f];
      short8 vf1 = *(const short8*)&Vsg[(32 + r31) * 72 + hi * 8 + 16 * f];
      o0 = __builtin_amdgcn_mfma_f32_32x32x16_bf16(pa[f], vf0, o0, 0, 0, 0);
      o1 = __builtin_amdgcn_mfma_f32_32x32x16_bf16(pa[f], vf1, o1, 0, 0, 0);
    }
  }

  // ---- combine KV-split halves: final = A + B (fixed order, exact linearity
  // of no-max softmax). lsc = group-half row sum (lane pair l, l+32 combine).
  float lsc = lsacc + __shfl_xor(lsacc, 32);
  __syncthreads();                        // all K/V reads done; smem reusable
  float* xch = (float*)smem;              // [4 waves][64 lanes][33] fp32
  float* xls = (float*)(smem + 33792);    // [4][32]
  float* lsb = (float*)(smem + 34304);    // [4][32] 1/ls broadcast
  if (g == 1) {
    int base = (wl * 64 + lane) * 33;
#pragma unroll
    for (int reg = 0; reg < 16; ++reg) {
      xch[base + reg] = o0[reg];
      xch[base + 16 + reg] = o1[reg];
    }
    if (lane < 32) xls[wl * 32 + r31] = lsc;
  }
  __syncthreads();
  if (g == 0) {
    int base = (wl * 64 + lane) * 33;
#pragma unroll
    for (int reg = 0; reg < 16; ++reg) {
      o0[reg] += xch[base + reg];
      o1[reg] += xch[base + 16 + reg];
    }
    float lst = lsc + xls[wl * 32 + r31];
    if (lane < 32) lsb[wl * 32 + r31] = 1.0f / lst;   // wave-private region,
                                                      // same-wave DS ordering
#pragma unroll
    for (int reg = 0; reg < 16; ++reg) {
      int r = (reg & 3) + 8 * (reg >> 2) + 4 * hi;
      float inv = lsb[wl * 32 + r];
      size_t row = (size_t)(b * 2048 + qb * 128 + wl * 32 + r);
      attnb[row * 512 + h * 64 + r31]      = bfr1(o0[reg] * inv);
      attnb[row * 512 + h * 64 + 32 + r31] = bfr1(o1[reg] * inv);
    }
  }
}

// ---------- zbuild: z[m][e*64+c] = sum_h mask_o[h,e] * attn[m][h*64+c] ----------
__global__ __launch_bounds__(64) void zbuild_kernel(
    const uint16_t* __restrict__ attnb, const uint32_t* __restrict__ gselw,
    uint16_t* __restrict__ zbuf)
{
  int m = blockIdx.x; int c = threadIdx.x;
  float acc[5] = {0.f, 0.f, 0.f, 0.f, 0.f};
#pragma unroll
  for (int h = 0; h < 8; ++h) {
    uint32_t sel = gselw[(m * 8 + h) * 4 + 3];
    int e1 = sel & 7, e2 = (sel >> 3) & 7;
    float a = bf2f(attnb[(size_t)m * 512 + h * 64 + c]);
#pragma unroll
    for (int e = 0; e < 5; ++e)
      acc[e] += (e == e1 || e == e2) ? a : 0.f;
  }
#pragma unroll
  for (int e = 0; e < 5; ++e)
    zbuf[(size_t)m * 320 + e * 64 + c] = bfr1(acc[e]);
}

// ---------- launch ----------
extern "C" void kernel_launch(void* const* d_in, const int* in_sizes, int n_in,
                              void* d_out, int out_size, void* d_ws, size_t ws_size,
                              hipStream_t stream) {
  const float* x  = (const float*)d_in[0];
  const float* Wq = (const float*)d_in[1];
  const float* Wk = (const float*)d_in[2];
  const float* Ws = (const float*)d_in[3];
  const float* Wd = (const float*)d_in[4];
  const float* Wv = (const float*)d_in[5];
  const float* Wo = (const float*)d_in[6];
  float* out = (float*)d_out;

  // workspace carve, lifetime-aliased; high-water 51,773,440 B
  char* ws = (char*)d_ws;
  uint4*    gsel  = (uint4*)   (ws);                  // [0, 1,048,576)
  uint16_t* WoT   = (uint16_t*)(ws + 1048576);        // [.., 1,703,936)
  uint16_t* Wt    = (uint16_t*)(ws + 1703936);        // [.., 4,587,520)  dead after proj
  uint16_t* xb    = (uint16_t*)(ws + 4587520);        // [.., 21,364,736) dead after proj
  uint16_t* proj  = (uint16_t*)(ws + 21364736);       // [.., 43,384,832)
  uint16_t* vt    = (uint16_t*)(ws + 43384832);       // [.., 51,773,440)
  uint16_t* attnb = (uint16_t*)(ws + 1703936);        // alias Wt+xb (dead)
  uint16_t* zbuf  = (uint16_t*)(ws + 10092544);       // alias xb tail

  gate_v6_kernel<<<dim3(MM / 64, 2), 1024, 0, stream>>>(x, Ws, Wd, (uint32_t*)gsel);
  pack_wt_kernel<<<dim3(16, 22), 256, 0, stream>>>(Wq, Wk, Wv, Wt);
  pack_wot_kernel<<<dim3(5, 16), 256, 0, stream>>>(Wo, WoT);
  xbf_kernel<<<(MM * DD / 4) / 256, 256, 0, stream>>>(x, xb);
  proj_mfma_kernel<<<dim3(NWT / 128, MM / 128), 256, 0, stream>>>(xb, Wt, proj);
  vbuild_kernel<<<32 * 32, 256, 0, stream>>>(proj, gsel, vt);
  flash_mfma_kernel<<<BB * HH * (TT / 128), 512, 0, stream>>>(proj, vt, attnb);
  zbuild_kernel<<<MM, 64, 0, stream>>>(attnb, (const uint32_t*)gsel, zbuf);
  out_mfma_kernel<<<dim3(DD / 128, MM / 128), 256, 0, stream>>>(zbuf, WoT, out);
}

// Round 9
// 230.403 us; speedup vs baseline: 1.4778x; 1.0266x over previous
//
#include <hip/hip_runtime.h>
#include <cstdint>
#include <cstddef>

// Problem constants
#define BB 4
#define TT 2048
#define DD 1024
#define HH 8
#define DH 64
#define EE 5
#define MM (BB*TT)          // 8192 rows
#define PLD 1344            // proj leading dim (q 512 | k 512 | xv 320)
#define NWT 1408            // padded N for MFMA proj (11 * 128)

typedef short short8 __attribute__((ext_vector_type(8)));
typedef float f32x4  __attribute__((ext_vector_type(4)));
typedef float f32x16 __attribute__((ext_vector_type(16)));
typedef unsigned int u32x2 __attribute__((ext_vector_type(2)));

// ---------- bf16 helpers ----------
__device__ __forceinline__ float bflo(uint32_t u) { union { uint32_t i; float f; } v; v.i = u << 16; return v.f; }
__device__ __forceinline__ float bfhi(uint32_t u) { union { uint32_t i; float f; } v; v.i = u & 0xFFFF0000u; return v.f; }
__device__ __forceinline__ float bf2f(uint16_t u) { union { uint32_t i; float f; } v; v.i = ((uint32_t)u) << 16; return v.f; }
// cheap bf16 pack: round-half-up (+0x8000) then v_perm_b32 pair-pack (1 op).
__device__ __forceinline__ uint32_t pkbf(float a, float b) {
  uint32_t ua = __float_as_uint(a) + 0x8000u;
  uint32_t ub = __float_as_uint(b) + 0x8000u;
  return __builtin_amdgcn_perm(ub, ua, 0x07060302u);  // [ua.b2,ua.b3,ub.b2,ub.b3]
}
__device__ __forceinline__ uint16_t bfr1(float f) {
  return (uint16_t)((__float_as_uint(f) + 0x8000u) >> 16);
}
// RNE pair-pack via hardware cvt (1 op); lo = a, hi = b
__device__ __forceinline__ uint32_t cvtpk(float a, float b) {
  uint32_t r;
  asm("v_cvt_pk_bf16_f32 %0, %1, %2" : "=v"(r) : "v"(a), "v"(b));
  return r;
}

// ---------- async global->LDS, 16B per lane (dest = wave base + lane*16) ----------
__device__ __forceinline__ void gload16(const void* g, void* l) {
  __builtin_amdgcn_global_load_lds(
      (const __attribute__((address_space(1))) uint32_t*)g,
      (__attribute__((address_space(3))) uint32_t*)l, 16, 0, 0);
}

// ---------- pack W^T bf16 [NWT][1024] for MFMA proj (LDS tile transpose) ----------
__global__ __launch_bounds__(256) void pack_wt_kernel(
    const float* __restrict__ Wq, const float* __restrict__ Wk,
    const float* __restrict__ Wv, uint16_t* __restrict__ Wt)
{
  __shared__ __align__(16) uint16_t Ts[64 * 68];
  int k0 = blockIdx.x * 64, n0 = blockIdx.y * 64;
  int t = threadIdx.x;
#pragma unroll
  for (int rep = 0; rep < 16; ++rep) {
    int li = rep * 256 + t;
    int kl = li >> 6, nl = li & 63;
    int k = k0 + kl, n = n0 + nl;
    float v = 0.f;
    if (n < 512)       v = Wq[k * 512 + n];
    else if (n < 1024) v = Wk[k * 512 + (n - 512)];
    else if (n < 1344) { int nn = n - 1024; v = Wv[((size_t)(nn >> 6) * 1024 + k) * 64 + (nn & 63)]; }
    Ts[kl * 68 + nl] = bfr1(v);
  }
  __syncthreads();
#pragma unroll
  for (int rep = 0; rep < 16; ++rep) {
    int li = rep * 256 + t;
    int nl = li >> 6, kl = li & 63;
    Wt[(size_t)(n0 + nl) * 1024 + k0 + kl] = Ts[kl * 68 + nl];
  }
}

// ---------- pack Wo[320][1024] fp32 -> WoT bf16 [1024][320] ----------
__global__ __launch_bounds__(256) void pack_wot_kernel(
    const float* __restrict__ Wo, uint16_t* __restrict__ WoT)
{
  __shared__ __align__(16) uint16_t Ts[64 * 68];
  int k0 = blockIdx.x * 64, n0 = blockIdx.y * 64;
  int t = threadIdx.x;
#pragma unroll
  for (int rep = 0; rep < 16; ++rep) {
    int li = rep * 256 + t;
    int kl = li >> 6, nl = li & 63;
    Ts[kl * 68 + nl] = bfr1(Wo[(size_t)(k0 + kl) * 1024 + n0 + nl]);
  }
  __syncthreads();
#pragma unroll
  for (int rep = 0; rep < 16; ++rep) {
    int li = rep * 256 + t;
    int nl = li >> 6, kl = li & 63;
    WoT[(size_t)(n0 + nl) * 320 + k0 + kl] = Ts[kl * 68 + nl];
  }
}

// ---------- top-2 of 5 (lax.top_k tie rule: lower index wins) ----------
__device__ __forceinline__ void top2_5(float g0, float g1, float g2, float g3, float g4,
                                       int& i1, float& b1, int& i2, float& b2) {
  i1 = 0; b1 = g0;
  if (g1 > b1) { b1 = g1; i1 = 1; }
  if (g2 > b1) { b1 = g2; i1 = 2; }
  if (g3 > b1) { b1 = g3; i1 = 3; }
  if (g4 > b1) { b1 = g4; i1 = 4; }
  i2 = -1; b2 = -__builtin_inff();
  if (i1 != 0 && g0 > b2) { b2 = g0; i2 = 0; }
  if (i1 != 1 && g1 > b2) { b2 = g1; i2 = 1; }
  if (i1 != 2 && g2 > b2) { b2 = g2; i2 = 2; }
  if (i1 != 3 && g3 > b2) { b2 = g3; i2 = 3; }
  if (i1 != 4 && g4 > b2) { b2 = g4; i2 = 4; }
}

// ---------- gate helpers: 20-wide uniform W batch + fma ----------
__device__ __forceinline__ void ldw20(float* d, const float* __restrict__ p) {
#pragma unroll
  for (int j = 0; j < 20; ++j) d[j] = p[j];
}
__device__ __forceinline__ void fma20(float* acc, const float* wv, float xv) {
#pragma unroll
  for (int j = 0; j < 20; ++j) acc[j] = fmaf(xv, wv[j], acc[j]);
}

// ---------- fused gate GEMM v7 (exact fp32, 8-way in-tile K-split, Ws/Wd
// split across blockIdx.y) + fused x->bf16 emission (replaces xbf_kernel;
// g==0 blocks emit xb with the IDENTICAL pkbf rounding -> bit-identical) ----------
__global__ __launch_bounds__(1024) void gate_v7_kernel(
    const float* __restrict__ x, const float* __restrict__ Ws,
    const float* __restrict__ Wd, uint32_t* __restrict__ gsel32,
    uint16_t* __restrict__ xb)
{
  __shared__ __align__(16) float xs[10752];   // 43,008 B; tiles use 64*132=8448
  int t = threadIdx.x;
  int m0 = blockIdx.x * 64;
  int g  = blockIdx.y;                         // 0 = Ws, 1 = Wd
  int w = t >> 6, lane = t & 63;
  int cg = __builtin_amdgcn_readfirstlane(w & 1);
  int kq = __builtin_amdgcn_readfirstlane(w >> 1);
  const float* __restrict__ Wg = g ? Wd : Ws;
  const float* __restrict__ wbase = Wg + (size_t)(kq * 16) * 40 + cg * 20;

  float acc[20];
#pragma unroll
  for (int j = 0; j < 20; ++j) acc[j] = 0.f;

  for (int tile = 0; tile < 8; ++tile) {
    __syncthreads();
    // stage x tile 64 rows x 128 k: float4 coalesced global, float4 LDS stores
#pragma unroll
    for (int rep = 0; rep < 2; ++rep) {
      int li = rep * 1024 + t;
      int row = li >> 5, kg = li & 31;
      size_t off = (size_t)(m0 + row) * 1024 + tile * 128 + kg * 4;
      float4 v = *(const float4*)&x[off];
      *(float4*)&xs[row * 132 + kg * 4] = v;
      if (g == 0) {                     // fused xb emission (uniform branch)
        uint2 o;
        o.x = pkbf(v.x, v.y);
        o.y = pkbf(v.z, v.w);
        *(uint2*)&xb[off] = o;
      }
    }
    __syncthreads();

    const float* wp = wbase + (size_t)tile * 128 * 40;
    const float* xp = &xs[lane * 132 + kq * 16];
    float wc[20], wn[20];
    ldw20(wc, wp);                       // k-local 0
#pragma unroll
    for (int k4 = 0; k4 < 4; ++k4) {     // 16 k per wave per tile
      float4 xv = *(const float4*)&xp[k4 * 4];
      ldw20(wn, wp + (size_t)(k4 * 4 + 1) * 40);
      fma20(acc, wc, xv.x);              // k = 4*k4+0
      ldw20(wc, wp + (size_t)(k4 * 4 + 2) * 40);
      fma20(acc, wn, xv.y);              // k = 4*k4+1
      ldw20(wn, wp + (size_t)(k4 * 4 + 3) * 40);
      fma20(acc, wc, xv.z);              // k = 4*k4+2
      if (k4 < 3) ldw20(wc, wp + (size_t)(k4 * 4 + 4) * 40);
      fma20(acc, wn, xv.w);              // k = 4*k4+3
    }
  }

  // ---- in-LDS 8-way K-split reduction, fixed tree, stride 21 ----
  float* red = xs;                       // reuse; 4 slots x 2 cg x 64 x 21
  __syncthreads();                       // xs (x tile) dead
  if (kq & 1) {                          // round 1 writers: kq 1,3,5,7
    int ro = (((kq >> 1) * 2 + cg) * 64 + lane) * 21;
#pragma unroll
    for (int j = 0; j < 20; ++j) red[ro + j] = acc[j];
  }
  __syncthreads();
  if (!(kq & 1)) {                       // round 1 readers: kq 0,2,4,6
    int ro = (((kq >> 1) * 2 + cg) * 64 + lane) * 21;
#pragma unroll
    for (int j = 0; j < 20; ++j) acc[j] += red[ro + j];
  }
  __syncthreads();
  if (kq == 2 || kq == 6) {              // round 2 writers
    int ro = (((kq >> 2) * 2 + cg) * 64 + lane) * 21;
#pragma unroll
    for (int j = 0; j < 20; ++j) red[ro + j] = acc[j];
  }
  __syncthreads();
  if (kq == 0 || kq == 4) {              // round 2 readers
    int ro = (((kq >> 2) * 2 + cg) * 64 + lane) * 21;
#pragma unroll
    for (int j = 0; j < 20; ++j) acc[j] += red[ro + j];
  }
  __syncthreads();
  if (kq == 4) {                         // round 3 writer
    int ro = (cg * 64 + lane) * 21;
#pragma unroll
    for (int j = 0; j < 20; ++j) red[ro + j] = acc[j];
  }
  __syncthreads();

  if (kq == 0) {
    int ro = (cg * 64 + lane) * 21;
#pragma unroll
    for (int j = 0; j < 20; ++j) acc[j] += red[ro + j];   // full sum
    int m = m0 + lane;
    if (g == 0) {      // Ws: V-expert selection + sigmoid weights (words 0-2)
#pragma unroll
      for (int hh = 0; hh < 4; ++hh) {
        int i1, i2; float b1, b2;
        top2_5(acc[hh * 5 + 0], acc[hh * 5 + 1], acc[hh * 5 + 2],
               acc[hh * 5 + 3], acc[hh * 5 + 4], i1, b1, i2, b2);
        float w1 = 1.f / (1.f + __expf(-b1));
        float w2 = 1.f / (1.f + __expf(-b2));
        uint32_t* gp = gsel32 + ((size_t)m * 8 + cg * 4 + hh) * 4;
        gp[0] = __float_as_uint(w1);
        gp[1] = __float_as_uint(w2);
        gp[2] = (uint32_t)(i1 | (i2 << 3));
      }
    } else {           // Wd: out-expert selection only (word 3)
#pragma unroll
      for (int hh = 0; hh < 4; ++hh) {
        int j1, j2; float c1, c2;
        top2_5(acc[hh * 5 + 0], acc[hh * 5 + 1], acc[hh * 5 + 2],
               acc[hh * 5 + 3], acc[hh * 5 + 4], j1, c1, j2, c2);
        uint32_t* gp = gsel32 + ((size_t)m * 8 + cg * 4 + hh) * 4;
        gp[3] = (uint32_t)(j1 | (j2 << 3));
      }
    }
  }
}

// ---------- proj MFMA GEMM (m97-style): global_load_lds into unpadded tiles ----------
__global__ __launch_bounds__(256) void proj_mfma_kernel(
    const uint16_t* __restrict__ xb, const uint16_t* __restrict__ Wt,
    uint16_t* __restrict__ proj)
{
  __shared__ __align__(16) uint16_t As[128 * 32];  // [m][k] unpadded (required by lds-DMA)
  __shared__ __align__(16) uint16_t Bs[128 * 32];  // [n][k]
  int t = threadIdx.x;
  int n0 = blockIdx.x * 128, m0 = blockIdx.y * 128;
  int w = t >> 6, lane = t & 63, q = lane >> 4, c = lane & 15;
  int wm = w & 1, wn = w >> 1;
  int lr = lane >> 2, lc = (lane & 3) * 8;   // 16 rows/chunk, 16B per lane
  f32x4 zf = {0.f, 0.f, 0.f, 0.f};
  f32x4 acc[4][4];
#pragma unroll
  for (int i = 0; i < 4; ++i)
#pragma unroll
    for (int j = 0; j < 4; ++j) acc[i][j] = zf;

  for (int kb = 0; kb < 32; ++kb) {
    __syncthreads();
#pragma unroll
    for (int j = 0; j < 2; ++j) {
      int row = w * 32 + j * 16 + lr;
      gload16(xb + (size_t)(m0 + row) * 1024 + kb * 32 + lc,
              &As[(w * 32 + j * 16) * 32 + lane * 8]);
      gload16(Wt + (size_t)(n0 + row) * 1024 + kb * 32 + lc,
              &Bs[(w * 32 + j * 16) * 32 + lane * 8]);
    }
    __syncthreads();
    short8 af[4], bfr[4];
#pragma unroll
    for (int i = 0; i < 4; ++i)
      af[i] = *(const short8*)&As[(wm * 64 + i * 16 + c) * 32 + q * 8];
#pragma unroll
    for (int j = 0; j < 4; ++j)
      bfr[j] = *(const short8*)&Bs[(wn * 64 + j * 16 + c) * 32 + q * 8];
#pragma unroll
    for (int i = 0; i < 4; ++i)
#pragma unroll
      for (int j = 0; j < 4; ++j)
        acc[i][j] = __builtin_amdgcn_mfma_f32_16x16x32_bf16(af[i], bfr[j], acc[i][j], 0, 0, 0);
  }
#pragma unroll
  for (int i = 0; i < 4; ++i)
#pragma unroll
    for (int j = 0; j < 4; ++j) {
      int col = n0 + wn * 64 + j * 16 + c;
      if (col < PLD) {
#pragma unroll
        for (int reg = 0; reg < 4; ++reg) {
          int row = m0 + wm * 64 + i * 16 + q * 4 + reg;
          proj[(size_t)row * PLD + col] = bfr1(acc[i][j][reg]);
        }
      }
    }
}

// ---------- out MFMA GEMM: zbuf[8192][320] @ WoT^T -> out fp32 [8192][1024] ----------
__global__ __launch_bounds__(256) void out_mfma_kernel(
    const uint16_t* __restrict__ zb, const uint16_t* __restrict__ WoT,
    float* __restrict__ out)
{
  __shared__ __align__(16) uint16_t As[128 * 32];
  __shared__ __align__(16) uint16_t Bs[128 * 32];
  int t = threadIdx.x;
  int n0 = blockIdx.x * 128, m0 = blockIdx.y * 128;
  int w = t >> 6, lane = t & 63, q = lane >> 4, c = lane & 15;
  int wm = w & 1, wn = w >> 1;
  int lr = lane >> 2, lc = (lane & 3) * 8;
  f32x4 zf = {0.f, 0.f, 0.f, 0.f};
  f32x4 acc[4][4];
#pragma unroll
  for (int i = 0; i < 4; ++i)
#pragma unroll
    for (int j = 0; j < 4; ++j) acc[i][j] = zf;

  for (int kb = 0; kb < 10; ++kb) {
    __syncthreads();
#pragma unroll
    for (int j = 0; j < 2; ++j) {
      int row = w * 32 + j * 16 + lr;
      gload16(zb + (size_t)(m0 + row) * 320 + kb * 32 + lc,
              &As[(w * 32 + j * 16) * 32 + lane * 8]);
      gload16(WoT + (size_t)(n0 + row) * 320 + kb * 32 + lc,
              &Bs[(w * 32 + j * 16) * 32 + lane * 8]);
    }
    __syncthreads();
    short8 af[4], bfr[4];
#pragma unroll
    for (int i = 0; i < 4; ++i)
      af[i] = *(const short8*)&As[(wm * 64 + i * 16 + c) * 32 + q * 8];
#pragma unroll
    for (int j = 0; j < 4; ++j)
      bfr[j] = *(const short8*)&Bs[(wn * 64 + j * 16 + c) * 32 + q * 8];
#pragma unroll
    for (int i = 0; i < 4; ++i)
#pragma unroll
      for (int j = 0; j < 4; ++j)
        acc[i][j] = __builtin_amdgcn_mfma_f32_16x16x32_bf16(af[i], bfr[j], acc[i][j], 0, 0, 0);
  }
#pragma unroll
  for (int i = 0; i < 4; ++i)
#pragma unroll
    for (int j = 0; j < 4; ++j) {
      int col = n0 + wn * 64 + j * 16 + c;
#pragma unroll
      for (int reg = 0; reg < 4; ++reg) {
        int row = m0 + wm * 64 + i * 16 + q * 4 + reg;
        out[(size_t)row * 1024 + col] = acc[i][j][reg];
      }
    }
}

// ---------- vbuild: v combine into d-major vt, TRUE j order (32x32 flash
// consumes V[j][d] via B-frag k = contiguous j) ----------
__global__ __launch_bounds__(256) void vbuild_kernel(
    const uint16_t* __restrict__ proj, const uint4* __restrict__ gsel,
    uint16_t* __restrict__ vt)
{
  int bi = blockIdx.x;            // 1024 = bh(32) x tb(32)
  int bh = bi >> 5, tb = bi & 31;
  int b = bh >> 3, h = bh & 7;
  int t = threadIdx.x;
  int tt = t & 63, dg = t >> 6;
  int m = b * 2048 + tb * 64 + tt;
  uint4 gs = gsel[m * 8 + h];
  float w1 = __uint_as_float(gs.x), w2 = __uint_as_float(gs.y);
  int i1 = gs.z & 7, i2 = (gs.z >> 3) & 7;
  const uint16_t* base = proj + (size_t)m * PLD + 1024;
  const uint4* p1 = (const uint4*)(base + i1 * 64 + dg * 16);
  const uint4* p2 = (const uint4*)(base + i2 * 64 + dg * 16);
  uint4 A0 = p1[0], A1 = p1[1], B0 = p2[0], B1 = p2[1];
  float v[16];
  v[0]  = w1*bflo(A0.x) + w2*bflo(B0.x); v[1]  = w1*bfhi(A0.x) + w2*bfhi(B0.x);
  v[2]  = w1*bflo(A0.y) + w2*bflo(B0.y); v[3]  = w1*bfhi(A0.y) + w2*bfhi(B0.y);
  v[4]  = w1*bflo(A0.z) + w2*bflo(B0.z); v[5]  = w1*bfhi(A0.z) + w2*bfhi(B0.z);
  v[6]  = w1*bflo(A0.w) + w2*bflo(B0.w); v[7]  = w1*bfhi(A0.w) + w2*bfhi(B0.w);
  v[8]  = w1*bflo(A1.x) + w2*bflo(B1.x); v[9]  = w1*bfhi(A1.x) + w2*bfhi(B1.x);
  v[10] = w1*bflo(A1.y) + w2*bflo(B1.y); v[11] = w1*bfhi(A1.y) + w2*bfhi(B1.y);
  v[12] = w1*bflo(A1.z) + w2*bflo(B1.z); v[13] = w1*bfhi(A1.z) + w2*bfhi(B1.z);
  v[14] = w1*bflo(A1.w) + w2*bflo(B1.w); v[15] = w1*bfhi(A1.w) + w2*bfhi(B1.w);
#pragma unroll
  for (int dd = 0; dd < 16; ++dd)
    vt[(size_t)(bh * 64 + dg * 16 + dd) * 2048 + tb * 64 + tt] = bfr1(v[dd]);
}

// ---------- flash per-tile compute (identical math to v5) ----------
__device__ __forceinline__ void flash_step(
    const uint16_t* Ksg, const uint16_t* Vsg,
    const short8 (&qf)[4], f32x16& o0, f32x16& o1, float& lsacc,
    int r31, int hi)
{
  short8 pa[4];
#pragma unroll
  for (int jg = 0; jg < 2; ++jg) {
    f32x16 s;
#pragma unroll
    for (int i = 0; i < 16; ++i) s[i] = 0.f;
#pragma unroll
    for (int f = 0; f < 4; ++f) {
      short8 kf = *(const short8*)&Ksg[(jg * 32 + r31) * 72 + hi * 8 + 16 * f];
      s = __builtin_amdgcn_mfma_f32_32x32x16_bf16(kf, qf[f], s, 0, 0, 0);
    }
    float p[16];
#pragma unroll
    for (int reg = 0; reg < 16; ++reg)
      p[reg] = __builtin_amdgcn_exp2f(s[reg] * 0.18033688f);
    lsacc += (((p[0] + p[1]) + (p[2] + p[3])) + ((p[4] + p[5]) + (p[6] + p[7])))
           + (((p[8] + p[9]) + (p[10] + p[11])) + ((p[12] + p[13]) + (p[14] + p[15])));
    uint32_t X1 = cvtpk(p[0], p[1]),  X2 = cvtpk(p[2], p[3]);
    uint32_t Y1 = cvtpk(p[4], p[5]),  Y2 = cvtpk(p[6], p[7]);
    uint32_t Z1 = cvtpk(p[8], p[9]),  Z2 = cvtpk(p[10], p[11]);
    uint32_t W1 = cvtpk(p[12], p[13]), W2 = cvtpk(p[14], p[15]);
    u32x2 s1 = __builtin_amdgcn_permlane32_swap(X1, Y1, false, false);
    u32x2 s2 = __builtin_amdgcn_permlane32_swap(X2, Y2, false, false);
    u32x2 s3 = __builtin_amdgcn_permlane32_swap(Z1, W1, false, false);
    u32x2 s4 = __builtin_amdgcn_permlane32_swap(Z2, W2, false, false);
    uint4 f0 = { s1.x, s2.x, s1.y, s2.y };   // j = jg*32 + hi*8 + 0..7
    uint4 f1 = { s3.x, s4.x, s3.y, s4.y };   // j = jg*32 + 16 + hi*8 + 0..7
    pa[jg * 2 + 0] = *(short8*)&f0;
    pa[jg * 2 + 1] = *(short8*)&f1;
  }
#pragma unroll
  for (int f = 0; f < 4; ++f) {
    short8 vf0 = *(const short8*)&Vsg[(r31) * 72 + hi * 8 + 16 * f];
    short8 vf1 = *(const short8*)&Vsg[(32 + r31) * 72 + hi * 8 + 16 * f];
    o0 = __builtin_amdgcn_mfma_f32_32x32x16_bf16(pa[f], vf0, o0, 0, 0, 0);
    o1 = __builtin_amdgcn_mfma_f32_32x32x16_bf16(pa[f], vf1, o1, 0, 0, 0);
  }
}

// ---------- flash attention v6: v5 + LDS double-buffer (ONE barrier/tile;
// ds_writes and global loads overlap compute). 2 KV-split groups x 4 waves,
// unrolled x2 so buffer names are static. No VGPR clamp (round-7 lesson). ----------
__global__ __launch_bounds__(512) void flash_mfma_kernel(
    const uint16_t* __restrict__ proj, const uint16_t* __restrict__ vt,
    uint16_t* __restrict__ attnb)
{
  // buf0: K[0,18432) V[18432,36864); buf1: K[36864,55296) V[55296,73728).
  // Epilogue overlays [0,34816) (buf0 region, dead after final barrier).
  __shared__ __align__(16) char smem[73728];
  int t = threadIdx.x;
  int bx = blockIdx.x;
  int qb = bx & 15, bh = bx >> 4;
  int h = bh & 7, b = bh >> 3;
  int g = t >> 8;                          // KV-split group
  int tg = t & 255;                        // thread within group
  int w = t >> 6, wl = w & 3;              // wave, wave-within-group
  int lane = t & 63;
  int r31 = lane & 31, hi = lane >> 5;
  int srow = tg >> 2, scq = tg & 3;

  uint16_t* K0 = (uint16_t*)(smem)         + g * 4608;
  uint16_t* V0 = (uint16_t*)(smem + 18432) + g * 4608;
  uint16_t* K1 = (uint16_t*)(smem + 36864) + g * 4608;
  uint16_t* V1 = (uint16_t*)(smem + 55296) + g * 4608;
  int so = srow * 72 + scq * 16;

  // Q B-fragments (persist): lane holds q-row r31 of this wave's 32-row group.
  short8 qf[4];
  {
    const uint16_t* qp = proj + (size_t)(b * 2048 + qb * 128 + wl * 32 + r31) * PLD + h * 64 + hi * 8;
#pragma unroll
    for (int f = 0; f < 4; ++f) qf[f] = *(const short8*)(qp + 16 * f);
  }

  f32x16 o0 = {0.f}, o1 = {0.f};
#pragma unroll
  for (int i = 0; i < 16; ++i) { o0[i] = 0.f; o1[i] = 0.f; }
  float lsacc = 0.f;

  // group g covers KV rows [g*1024, g*1024+1024) = tiles 0..15 local.
  const uint16_t* kg = proj + (size_t)(b * 2048 + g * 1024 + srow) * PLD + 512 + h * 64 + scq * 16;
  const uint16_t* vg = vt + (size_t)(bh * 64 + srow) * 2048 + g * 1024 + scq * 16;

  // prologue: tile0 -> buf0; load tile1 into regs
  uint4 kp0, kp1, vp0, vp1;
  kp0 = ((const uint4*)kg)[0]; kp1 = ((const uint4*)kg)[1];
  vp0 = ((const uint4*)vg)[0]; vp1 = ((const uint4*)vg)[1];
  *(uint4*)&K0[so] = kp0; *(uint4*)&K0[so + 8] = kp1;
  *(uint4*)&V0[so] = vp0; *(uint4*)&V0[so + 8] = vp1;
  {
    const uint4* pk = (const uint4*)(kg + (size_t)64 * PLD);
    kp0 = pk[0]; kp1 = pk[1];
    const uint4* pv = (const uint4*)(vg + 64);
    vp0 = pv[0]; vp1 = pv[1];
  }
  __syncthreads();

  for (int it2 = 0; it2 < 8; ++it2) {
    // even tile 2*it2: stage tile 2*it2+1 -> buf1, prefetch 2*it2+2, compute buf0
    *(uint4*)&K1[so] = kp0; *(uint4*)&K1[so + 8] = kp1;
    *(uint4*)&V1[so] = vp0; *(uint4*)&V1[so + 8] = vp1;
    if (it2 < 7) {
      const uint4* pk = (const uint4*)(kg + (size_t)(2 * it2 + 2) * 64 * PLD);
      kp0 = pk[0]; kp1 = pk[1];
      const uint4* pv = (const uint4*)(vg + (2 * it2 + 2) * 64);
      vp0 = pv[0]; vp1 = pv[1];
    }
    flash_step(K0, V0, qf, o0, o1, lsacc, r31, hi);
    __syncthreads();
    // odd tile 2*it2+1: stage tile 2*it2+2 -> buf0, prefetch 2*it2+3, compute buf1
    if (it2 < 7) {
      *(uint4*)&K0[so] = kp0; *(uint4*)&K0[so + 8] = kp1;
      *(uint4*)&V0[so] = vp0; *(uint4*)&V0[so + 8] = vp1;
      const uint4* pk = (const uint4*)(kg + (size_t)(2 * it2 + 3) * 64 * PLD);
      kp0 = pk[0]; kp1 = pk[1];
      const uint4* pv = (const uint4*)(vg + (2 * it2 + 3) * 64);
      vp0 = pv[0]; vp1 = pv[1];
    }
    flash_step(K1, V1, qf, o0, o1, lsacc, r31, hi);
    __syncthreads();
  }

  // ---- combine KV-split halves: final = A + B (fixed order, exact linearity
  // of no-max softmax). Final loop barrier already retired all K/V reads.
  float lsc = lsacc + __shfl_xor(lsacc, 32);
  float* xch = (float*)smem;              // [4 waves][64 lanes][33] fp32
  float* xls = (float*)(smem + 33792);    // [4][32]
  float* lsb = (float*)(smem + 34304);    // [4][32] 1/ls broadcast
  if (g == 1) {
    int base = (wl * 64 + lane) * 33;
#pragma unroll
    for (int reg = 0; reg < 16; ++reg) {
      xch[base + reg] = o0[reg];
      xch[base + 16 + reg] = o1[reg];
    }
    if (lane < 32) xls[wl * 32 + r31] = lsc;
  }
  __syncthreads();
  if (g == 0) {
    int base = (wl * 64 + lane) * 33;
#pragma unroll
    for (int reg = 0; reg < 16; ++reg) {
      o0[reg] += xch[base + reg];
      o1[reg] += xch[base + 16 + reg];
    }
    float lst = lsc + xls[wl * 32 + r31];
    if (lane < 32) lsb[wl * 32 + r31] = 1.0f / lst;   // wave-private region,
                                                      // same-wave DS ordering
#pragma unroll
    for (int reg = 0; reg < 16; ++reg) {
      int r = (reg & 3) + 8 * (reg >> 2) + 4 * hi;
      float inv = lsb[wl * 32 + r];
      size_t row = (size_t)(b * 2048 + qb * 128 + wl * 32 + r);
      attnb[row * 512 + h * 64 + r31]      = bfr1(o0[reg] * inv);
      attnb[row * 512 + h * 64 + 32 + r31] = bfr1(o1[reg] * inv);
    }
  }
}

// ---------- zbuild: z[m][e*64+c] = sum_h mask_o[h,e] * attn[m][h*64+c] ----------
__global__ __launch_bounds__(64) void zbuild_kernel(
    const uint16_t* __restrict__ attnb, const uint32_t* __restrict__ gselw,
    uint16_t* __restrict__ zbuf)
{
  int m = blockIdx.x; int c = threadIdx.x;
  float acc[5] = {0.f, 0.f, 0.f, 0.f, 0.f};
#pragma unroll
  for (int h = 0; h < 8; ++h) {
    uint32_t sel = gselw[(m * 8 + h) * 4 + 3];
    int e1 = sel & 7, e2 = (sel >> 3) & 7;
    float a = bf2f(attnb[(size_t)m * 512 + h * 64 + c]);
#pragma unroll
    for (int e = 0; e < 5; ++e)
      acc[e] += (e == e1 || e == e2) ? a : 0.f;
  }
#pragma unroll
  for (int e = 0; e < 5; ++e)
    zbuf[(size_t)m * 320 + e * 64 + c] = bfr1(acc[e]);
}

// ---------- launch ----------
extern "C" void kernel_launch(void* const* d_in, const int* in_sizes, int n_in,
                              void* d_out, int out_size, void* d_ws, size_t ws_size,
                              hipStream_t stream) {
  const float* x  = (const float*)d_in[0];
  const float* Wq = (const float*)d_in[1];
  const float* Wk = (const float*)d_in[2];
  const float* Ws = (const float*)d_in[3];
  const float* Wd = (const float*)d_in[4];
  const float* Wv = (const float*)d_in[5];
  const float* Wo = (const float*)d_in[6];
  float* out = (float*)d_out;

  // workspace carve, lifetime-aliased; high-water 51,773,440 B
  char* ws = (char*)d_ws;
  uint4*    gsel  = (uint4*)   (ws);                  // [0, 1,048,576)
  uint16_t* WoT   = (uint16_t*)(ws + 1048576);        // [.., 1,703,936)
  uint16_t* Wt    = (uint16_t*)(ws + 1703936);        // [.., 4,587,520)  dead after proj
  uint16_t* xb    = (uint16_t*)(ws + 4587520);        // [.., 21,364,736) dead after proj
  uint16_t* proj  = (uint16_t*)(ws + 21364736);       // [.., 43,384,832)
  uint16_t* vt    = (uint16_t*)(ws + 43384832);       // [.., 51,773,440)
  uint16_t* attnb = (uint16_t*)(ws + 1703936);        // alias Wt+xb (dead)
  uint16_t* zbuf  = (uint16_t*)(ws + 10092544);       // alias xb tail

  gate_v7_kernel<<<dim3(MM / 64, 2), 1024, 0, stream>>>(x, Ws, Wd, (uint32_t*)gsel, xb);
  pack_wt_kernel<<<dim3(16, 22), 256, 0, stream>>>(Wq, Wk, Wv, Wt);
  pack_wot_kernel<<<dim3(5, 16), 256, 0, stream>>>(Wo, WoT);
  proj_mfma_kernel<<<dim3(NWT / 128, MM / 128), 256, 0, stream>>>(xb, Wt, proj);
  vbuild_kernel<<<32 * 32, 256, 0, stream>>>(proj, gsel, vt);
  flash_mfma_kernel<<<BB * HH * (TT / 128), 512, 0, stream>>>(proj, vt, attnb);
  zbuild_kernel<<<MM, 64, 0, stream>>>(attnb, (const uint32_t*)gsel, zbuf);
  out_mfma_kernel<<<dim3(DD / 128, MM / 128), 256, 0, stream>>>(zbuf, WoT, out);
}